// Round 1
// baseline (176.572 us; speedup 1.0000x reference)
//
#include <hip/hip_runtime.h>
#include <math.h>

#define KK 512
#define DD 512
#define HH 512
#define PD 128
#define KM1 511
#define LN_EPS 1e-5f

__device__ __forceinline__ float wave_reduce_sum(float v) {
    #pragma unroll
    for (int off = 32; off > 0; off >>= 1)
        v += __shfl_xor(v, off, 64);
    return v;
}

// ---- generic 32x32 tiled transpose: src (R x C) -> dst (C x R) ----
__global__ void transpose_kernel(const float* __restrict__ src, float* __restrict__ dst,
                                 int R, int C) {
    __shared__ float tile[32][33];
    int tx = threadIdx.x, ty = threadIdx.y;       // block (32, 8)
    int c0 = blockIdx.x * 32, r0 = blockIdx.y * 32;
    #pragma unroll
    for (int i = 0; i < 4; i++)
        tile[ty + i * 8][tx] = src[(size_t)(r0 + ty + i * 8) * C + c0 + tx];
    __syncthreads();
    #pragma unroll
    for (int i = 0; i < 4; i++)
        dst[(size_t)(c0 + ty + i * 8) * R + r0 + tx] = tile[tx][ty + i * 8];
}

// ---- sa[k] = x[k,:]·wa, sb[k] = x[k,:]·wb ----
__global__ __launch_bounds__(64) void sab_kernel(const float* __restrict__ x,
                                                 const float* __restrict__ W_att,
                                                 float* __restrict__ sa,
                                                 float* __restrict__ sb) {
    int k = blockIdx.x;
    int lane = threadIdx.x;  // 64
    const float4* xr = (const float4*)(x + (size_t)k * DD);
    const float4* wa = (const float4*)(W_att);
    const float4* wb = (const float4*)(W_att + DD);
    float pa = 0.f, pb = 0.f;
    #pragma unroll
    for (int i = 0; i < 2; i++) {
        float4 xv = xr[lane + i * 64];
        float4 av = wa[lane + i * 64];
        float4 bv = wb[lane + i * 64];
        pa += xv.x * av.x + xv.y * av.y + xv.z * av.z + xv.w * av.w;
        pb += xv.x * bv.x + xv.y * bv.y + xv.z * bv.z + xv.w * bv.w;
    }
    pa = wave_reduce_sum(pa);
    pb = wave_reduce_sum(pb);
    if (lane == 0) { sa[k] = pa; sb[k] = pb; }
}

// ---- the single streaming pass over pair_feats ----
// per block: one k. Computes alpha (stored into dense A with zero diag),
// apf[k,p] = sum_t alpha*pf[k,t,p], asum[k] = sum_t alpha.
__global__ __launch_bounds__(512) void pair_pass_kernel(
    const float* __restrict__ pf, const float* __restrict__ sa,
    const float* __restrict__ sb, const float* __restrict__ W_att,
    const float* __restrict__ b_att, float* __restrict__ A,
    float* __restrict__ apf, float* __restrict__ asum) {
    int k = blockIdx.x;
    int tid = threadIdx.x;
    int w = tid >> 6, lane = tid & 63;
    float2 wc = ((const float2*)(W_att + 2 * DD))[lane];  // wc[2*lane], wc[2*lane+1]
    float sak = sa[k];
    float batt = b_att[0];
    float a0 = 0.f, a1 = 0.f, asl = 0.f;
    const float2* pfk = (const float2*)(pf + (size_t)k * KM1 * PD);
    for (int t = w; t < KM1; t += 8) {
        float2 v = pfk[(size_t)t * 64 + lane];
        float part = v.x * wc.x + v.y * wc.y;
        part = wave_reduce_sum(part);           // sc, broadcast to all lanes
        int j = t + (t >= k);
        float z = sak + sb[j] + part + batt;
        float alpha = 1.f / (1.f + expf(-z));
        if (lane == 0) A[(size_t)k * KK + j] = alpha;
        a0 += alpha * v.x;
        a1 += alpha * v.y;
        asl += alpha;
    }
    __shared__ float apf_s[8][128];
    __shared__ float asum_s[8];
    apf_s[w][2 * lane]     = a0;
    apf_s[w][2 * lane + 1] = a1;
    if (lane == 0) asum_s[w] = asl;
    __syncthreads();
    if (tid < PD) {
        float s = 0.f;
        #pragma unroll
        for (int i = 0; i < 8; i++) s += apf_s[i][tid];
        apf[(size_t)k * PD + tid] = s;
    }
    if (tid == 0) {
        float s = 0.f;
        #pragma unroll
        for (int i = 0; i < 8; i++) s += asum_s[i];
        asum[k] = s;
        A[(size_t)k * KK + k] = 0.f;  // diagonal excluded
    }
}

// ---- oj[k,h] = x[k,:]·W_obj[h,:] + b_obj[h]  (uses W_objT for coalescing) ----
__global__ __launch_bounds__(512) void oj_kernel(const float* __restrict__ x,
                                                 const float* __restrict__ W_objT,
                                                 const float* __restrict__ b_obj,
                                                 float* __restrict__ oj) {
    int k0 = blockIdx.x * 4;
    int h = threadIdx.x;
    __shared__ float xs[4][512];
    #pragma unroll
    for (int r = 0; r < 4; r++) xs[r][h] = x[(size_t)(k0 + r) * DD + h];
    __syncthreads();
    float acc[4] = {0.f, 0.f, 0.f, 0.f};
    for (int j = 0; j < DD; j++) {
        float wv = W_objT[(size_t)j * HH + h];
        #pragma unroll
        for (int r = 0; r < 4; r++) acc[r] += xs[r][j] * wv;
    }
    float bo = b_obj[h];
    #pragma unroll
    for (int r = 0; r < 4; r++) oj[(size_t)(k0 + r) * HH + h] = acc[r] + bo;
}

// ---- messages + residual + LayerNorm 1 -> out1 ----
__global__ __launch_bounds__(512) void msg_ln1_kernel(
    const float* __restrict__ x, const float* __restrict__ A,
    const float* __restrict__ oj, const float* __restrict__ apf,
    const float* __restrict__ asum, const float* __restrict__ W_pairT,
    const float* __restrict__ b_pair, const float* __restrict__ ln_g,
    const float* __restrict__ ln_b, float* __restrict__ out1) {
    int k0 = blockIdx.x * 4;
    int h = threadIdx.x;
    int w = h >> 6, lane = h & 63;
    __shared__ float As[4][512];
    __shared__ float apfs[4][128];
    #pragma unroll
    for (int r = 0; r < 4; r++) As[r][h] = A[(size_t)(k0 + r) * KK + h];
    { int r = h >> 7, p = h & 127; apfs[r][p] = apf[(size_t)(k0 + r) * PD + p]; }
    __syncthreads();
    float acc[4] = {0.f, 0.f, 0.f, 0.f};
    for (int j = 0; j < KK; j++) {
        float o = oj[(size_t)j * HH + h];
        #pragma unroll
        for (int r = 0; r < 4; r++) acc[r] += As[r][j] * o;
    }
    for (int p = 0; p < PD; p++) {
        float wp = W_pairT[(size_t)p * HH + h];
        #pragma unroll
        for (int r = 0; r < 4; r++) acc[r] += apfs[r][p] * wp;
    }
    float bp = b_pair[h];
    float g = ln_g[h], bb = ln_b[h];
    __shared__ float red1[8][4], red2[8][4];
    float vout[4];
    #pragma unroll
    for (int r = 0; r < 4; r++) {
        float v = x[(size_t)(k0 + r) * DD + h] +
                  (acc[r] + asum[k0 + r] * bp) * (1.0f / KM1);
        vout[r] = v;
        float s1 = wave_reduce_sum(v);
        float s2 = wave_reduce_sum(v * v);
        if (lane == 0) { red1[w][r] = s1; red2[w][r] = s2; }
    }
    __syncthreads();
    #pragma unroll
    for (int r = 0; r < 4; r++) {
        float S1 = 0.f, S2 = 0.f;
        #pragma unroll
        for (int i = 0; i < 8; i++) { S1 += red1[i][r]; S2 += red2[i][r]; }
        float mu  = S1 * (1.0f / HH);
        float var = S2 * (1.0f / HH) - mu * mu;
        out1[(size_t)(k0 + r) * HH + h] = g * (vout[r] - mu) * rsqrtf(var + LN_EPS) + bb;
    }
}

// ---- ffn hidden: h1 = relu(out1 @ W1.T + b1) ----
__global__ __launch_bounds__(512) void ffn1_kernel(const float* __restrict__ out1,
                                                   const float* __restrict__ W1T,
                                                   const float* __restrict__ b1,
                                                   float* __restrict__ h1) {
    int k0 = blockIdx.x * 4;
    int h = threadIdx.x;
    __shared__ float os[4][512];
    #pragma unroll
    for (int r = 0; r < 4; r++) os[r][h] = out1[(size_t)(k0 + r) * HH + h];
    __syncthreads();
    float acc[4] = {0.f, 0.f, 0.f, 0.f};
    for (int j = 0; j < HH; j++) {
        float wv = W1T[(size_t)j * HH + h];
        #pragma unroll
        for (int r = 0; r < 4; r++) acc[r] += os[r][j] * wv;
    }
    float b = b1[h];
    #pragma unroll
    for (int r = 0; r < 4; r++)
        h1[(size_t)(k0 + r) * HH + h] = fmaxf(acc[r] + b, 0.f);
}

// ---- ffn out + residual + LayerNorm 2 -> out ----
__global__ __launch_bounds__(512) void ffn2_ln2_kernel(
    const float* __restrict__ h1, const float* __restrict__ W2T,
    const float* __restrict__ b2, const float* __restrict__ out1,
    const float* __restrict__ ln_g, const float* __restrict__ ln_b,
    float* __restrict__ out) {
    int k0 = blockIdx.x * 4;
    int h = threadIdx.x;
    int w = h >> 6, lane = h & 63;
    __shared__ float hs[4][512];
    #pragma unroll
    for (int r = 0; r < 4; r++) hs[r][h] = h1[(size_t)(k0 + r) * HH + h];
    __syncthreads();
    float acc[4] = {0.f, 0.f, 0.f, 0.f};
    for (int j = 0; j < HH; j++) {
        float wv = W2T[(size_t)j * HH + h];
        #pragma unroll
        for (int r = 0; r < 4; r++) acc[r] += hs[r][j] * wv;
    }
    float b = b2[h];
    float g = ln_g[h], bb = ln_b[h];
    __shared__ float red1[8][4], red2[8][4];
    float vout[4];
    #pragma unroll
    for (int r = 0; r < 4; r++) {
        float v = out1[(size_t)(k0 + r) * HH + h] + acc[r] + b;
        vout[r] = v;
        float s1 = wave_reduce_sum(v);
        float s2 = wave_reduce_sum(v * v);
        if (lane == 0) { red1[w][r] = s1; red2[w][r] = s2; }
    }
    __syncthreads();
    #pragma unroll
    for (int r = 0; r < 4; r++) {
        float S1 = 0.f, S2 = 0.f;
        #pragma unroll
        for (int i = 0; i < 8; i++) { S1 += red1[i][r]; S2 += red2[i][r]; }
        float mu  = S1 * (1.0f / HH);
        float var = S2 * (1.0f / HH) - mu * mu;
        out[(size_t)(k0 + r) * HH + h] = g * (vout[r] - mu) * rsqrtf(var + LN_EPS) + bb;
    }
}

extern "C" void kernel_launch(void* const* d_in, const int* in_sizes, int n_in,
                              void* d_out, int out_size, void* d_ws, size_t ws_size,
                              hipStream_t stream) {
    const float* x          = (const float*)d_in[0];
    const float* pair_feats = (const float*)d_in[1];
    const float* W_att      = (const float*)d_in[2];
    const float* b_att      = (const float*)d_in[3];
    const float* W_obj      = (const float*)d_in[4];
    const float* b_obj      = (const float*)d_in[5];
    const float* W_pair     = (const float*)d_in[6];
    const float* b_pair     = (const float*)d_in[7];
    const float* ln_g       = (const float*)d_in[8];
    const float* ln_b       = (const float*)d_in[9];
    const float* W1         = (const float*)d_in[10];
    const float* b1         = (const float*)d_in[11];
    const float* W2         = (const float*)d_in[12];
    const float* b2         = (const float*)d_in[13];
    float* out = (float*)d_out;

    float* ws      = (float*)d_ws;
    float* W_objT  = ws;                    // 512*512
    float* W1T     = W_objT + 512 * 512;    // 512*512
    float* W2T     = W1T + 512 * 512;       // 512*512
    float* W_pairT = W2T + 512 * 512;       // 128*512
    float* sa      = W_pairT + 128 * 512;   // 512
    float* sb      = sa + 512;              // 512
    float* A       = sb + 512;              // 512*512
    float* apf     = A + 512 * 512;         // 512*128
    float* asum    = apf + 512 * 128;       // 512
    float* oj      = asum + 512;            // 512*512
    float* out1    = oj + 512 * 512;        // 512*512
    float* h1      = out1 + 512 * 512;      // 512*512

    dim3 tb(32, 8);
    transpose_kernel<<<dim3(16, 16), tb, 0, stream>>>(W_obj, W_objT, 512, 512);
    transpose_kernel<<<dim3(4, 16), tb, 0, stream>>>(W_pair, W_pairT, 512, 128);
    transpose_kernel<<<dim3(16, 16), tb, 0, stream>>>(W1, W1T, 512, 512);
    transpose_kernel<<<dim3(16, 16), tb, 0, stream>>>(W2, W2T, 512, 512);

    sab_kernel<<<512, 64, 0, stream>>>(x, W_att, sa, sb);
    pair_pass_kernel<<<512, 512, 0, stream>>>(pair_feats, sa, sb, W_att, b_att, A, apf, asum);
    oj_kernel<<<128, 512, 0, stream>>>(x, W_objT, b_obj, oj);
    msg_ln1_kernel<<<128, 512, 0, stream>>>(x, A, oj, apf, asum, W_pairT, b_pair, ln_g, ln_b, out1);
    ffn1_kernel<<<128, 512, 0, stream>>>(out1, W1T, b1, h1);
    ffn2_ln2_kernel<<<128, 512, 0, stream>>>(h1, W2T, b2, out1, ln_g, ln_b, out);
}

// Round 2
// 154.380 us; speedup vs baseline: 1.1437x; 1.1437x over previous
//
#include <hip/hip_runtime.h>
#include <math.h>

#define KK 512
#define DD 512
#define HH 512
#define PD 128
#define KM1 511
#define LN_EPS 1e-5f
#define NCHUNK 4
#define CHUNK_T 128

__device__ __forceinline__ float wave_reduce_sum(float v) {
    #pragma unroll
    for (int off = 32; off > 0; off >>= 1)
        v += __shfl_xor(v, off, 64);
    return v;
}

// reduce within 32-lane half-groups (xor masks < 32 stay inside each half)
__device__ __forceinline__ float half_reduce_sum(float v) {
    #pragma unroll
    for (int off = 16; off > 0; off >>= 1)
        v += __shfl_xor(v, off, 64);
    return v;
}

// ---- generic 32x32 tiled transpose: src (R x C) -> dst (C x R) ----
__global__ void transpose_kernel(const float* __restrict__ src, float* __restrict__ dst,
                                 int R, int C) {
    __shared__ float tile[32][33];
    int tx = threadIdx.x, ty = threadIdx.y;       // block (32, 8)
    int c0 = blockIdx.x * 32, r0 = blockIdx.y * 32;
    #pragma unroll
    for (int i = 0; i < 4; i++)
        tile[ty + i * 8][tx] = src[(size_t)(r0 + ty + i * 8) * C + c0 + tx];
    __syncthreads();
    #pragma unroll
    for (int i = 0; i < 4; i++)
        dst[(size_t)(c0 + ty + i * 8) * R + r0 + tx] = tile[tx][ty + i * 8];
}

// ---- sa[k] = x[k,:]·wa, sb[k] = x[k,:]·wb ----
__global__ __launch_bounds__(64) void sab_kernel(const float* __restrict__ x,
                                                 const float* __restrict__ W_att,
                                                 float* __restrict__ sa,
                                                 float* __restrict__ sb) {
    int k = blockIdx.x;
    int lane = threadIdx.x;  // 64
    const float4* xr = (const float4*)(x + (size_t)k * DD);
    const float4* wa = (const float4*)(W_att);
    const float4* wb = (const float4*)(W_att + DD);
    float pa = 0.f, pb = 0.f;
    #pragma unroll
    for (int i = 0; i < 2; i++) {
        float4 xv = xr[lane + i * 64];
        float4 av = wa[lane + i * 64];
        float4 bv = wb[lane + i * 64];
        pa += xv.x * av.x + xv.y * av.y + xv.z * av.z + xv.w * av.w;
        pb += xv.x * bv.x + xv.y * bv.y + xv.z * bv.z + xv.w * bv.w;
    }
    pa = wave_reduce_sum(pa);
    pb = wave_reduce_sum(pb);
    if (lane == 0) { sa[k] = pa; sb[k] = pb; }
}

// ---- streaming pass over pair_feats, split-k over t-chunks ----
// block (k, chunk): 128 t-rows. float4/lane, 2 rows per wave (32-lane halves).
// Writes alpha into dense A (disjoint per chunk), partial apf/asum per chunk.
__global__ __launch_bounds__(512) void pair_pass_kernel(
    const float* __restrict__ pf, const float* __restrict__ sa,
    const float* __restrict__ sb, const float* __restrict__ W_att,
    const float* __restrict__ b_att, float* __restrict__ A,
    float* __restrict__ apf_part, float* __restrict__ asum_part) {
    int k = blockIdx.x;
    int chunk = blockIdx.y;
    int tbase = chunk * CHUNK_T;
    int tid = threadIdx.x;
    int w = tid >> 6;            // wave 0..7
    int lane = tid & 63;
    int h = lane >> 5;           // half 0/1
    int c = lane & 31;           // float4 column 0..31
    int g = w * 2 + h;           // group 0..15

    float4 wc4 = ((const float4*)(W_att + 2 * DD))[c];
    float sak = sa[k];
    float batt = b_att[0];
    float4 a4 = make_float4(0.f, 0.f, 0.f, 0.f);
    float asl = 0.f;
    const float4* pfk = (const float4*)(pf + (size_t)k * KM1 * PD);

    #pragma unroll
    for (int it = 0; it < 8; it++) {
        int t = tbase + it * 16 + g;
        if (t < KM1) {
            float4 v = pfk[(size_t)t * 32 + c];
            float part = v.x * wc4.x + v.y * wc4.y + v.z * wc4.z + v.w * wc4.w;
            part = half_reduce_sum(part);       // sc, broadcast within 32-lane half
            int j = t + (t >= k);
            float z = sak + sb[j] + part + batt;
            float alpha = 1.f / (1.f + __expf(-z));
            if (c == 0) A[(size_t)k * KK + j] = alpha;
            a4.x += alpha * v.x;
            a4.y += alpha * v.y;
            a4.z += alpha * v.z;
            a4.w += alpha * v.w;
            asl += alpha;
        }
    }

    __shared__ float apf_s[16][128];
    __shared__ float asum_s[16];
    apf_s[g][4 * c + 0] = a4.x;
    apf_s[g][4 * c + 1] = a4.y;
    apf_s[g][4 * c + 2] = a4.z;
    apf_s[g][4 * c + 3] = a4.w;
    if (c == 0) asum_s[g] = asl;   // every lane in half has same alpha history
    __syncthreads();
    if (tid < PD) {
        float s = 0.f;
        #pragma unroll
        for (int i = 0; i < 16; i++) s += apf_s[i][tid];
        apf_part[((size_t)chunk * KK + k) * PD + tid] = s;
    }
    if (tid == 0) {
        float s = 0.f;
        #pragma unroll
        for (int i = 0; i < 16; i++) s += asum_s[i];
        asum_part[(size_t)chunk * KK + k] = s;
        if (chunk == 0) A[(size_t)k * KK + k] = 0.f;   // diagonal excluded
    }
}

// ---- oj[k,h] = x[k,:]·W_obj[h,:] + b_obj[h]  (uses W_objT for coalescing) ----
__global__ __launch_bounds__(512) void oj_kernel(const float* __restrict__ x,
                                                 const float* __restrict__ W_objT,
                                                 const float* __restrict__ b_obj,
                                                 float* __restrict__ oj) {
    int k0 = blockIdx.x * 4;
    int h = threadIdx.x;
    __shared__ float xs[4][512];
    #pragma unroll
    for (int r = 0; r < 4; r++) xs[r][h] = x[(size_t)(k0 + r) * DD + h];
    __syncthreads();
    float acc[4] = {0.f, 0.f, 0.f, 0.f};
    for (int j = 0; j < DD; j++) {
        float wv = W_objT[(size_t)j * HH + h];
        #pragma unroll
        for (int r = 0; r < 4; r++) acc[r] += xs[r][j] * wv;
    }
    float bo = b_obj[h];
    #pragma unroll
    for (int r = 0; r < 4; r++) oj[(size_t)(k0 + r) * HH + h] = acc[r] + bo;
}

// ---- messages + residual + LayerNorm 1 -> out1 ----
__global__ __launch_bounds__(512) void msg_ln1_kernel(
    const float* __restrict__ x, const float* __restrict__ A,
    const float* __restrict__ oj, const float* __restrict__ apf_part,
    const float* __restrict__ asum_part, const float* __restrict__ W_pairT,
    const float* __restrict__ b_pair, const float* __restrict__ ln_g,
    const float* __restrict__ ln_b, float* __restrict__ out1) {
    int k0 = blockIdx.x * 4;
    int h = threadIdx.x;
    int w = h >> 6, lane = h & 63;
    __shared__ float As[4][512];
    __shared__ float apfs[4][128];
    __shared__ float asums[4];
    #pragma unroll
    for (int r = 0; r < 4; r++) As[r][h] = A[(size_t)(k0 + r) * KK + h];
    { int r = h >> 7, p = h & 127;
      float s = 0.f;
      #pragma unroll
      for (int cch = 0; cch < NCHUNK; cch++)
          s += apf_part[((size_t)cch * KK + (k0 + r)) * PD + p];
      apfs[r][p] = s; }
    if (h < 4) {
        float s = 0.f;
        #pragma unroll
        for (int cch = 0; cch < NCHUNK; cch++)
            s += asum_part[(size_t)cch * KK + (k0 + h)];
        asums[h] = s;
    }
    __syncthreads();
    float acc[4] = {0.f, 0.f, 0.f, 0.f};
    for (int j = 0; j < KK; j++) {
        float o = oj[(size_t)j * HH + h];
        #pragma unroll
        for (int r = 0; r < 4; r++) acc[r] += As[r][j] * o;
    }
    for (int p = 0; p < PD; p++) {
        float wp = W_pairT[(size_t)p * HH + h];
        #pragma unroll
        for (int r = 0; r < 4; r++) acc[r] += apfs[r][p] * wp;
    }
    float bp = b_pair[h];
    float g = ln_g[h], bb = ln_b[h];
    __shared__ float red1[8][4], red2[8][4];
    float vout[4];
    #pragma unroll
    for (int r = 0; r < 4; r++) {
        float v = x[(size_t)(k0 + r) * DD + h] +
                  (acc[r] + asums[r] * bp) * (1.0f / KM1);
        vout[r] = v;
        float s1 = wave_reduce_sum(v);
        float s2 = wave_reduce_sum(v * v);
        if (lane == 0) { red1[w][r] = s1; red2[w][r] = s2; }
    }
    __syncthreads();
    #pragma unroll
    for (int r = 0; r < 4; r++) {
        float S1 = 0.f, S2 = 0.f;
        #pragma unroll
        for (int i = 0; i < 8; i++) { S1 += red1[i][r]; S2 += red2[i][r]; }
        float mu  = S1 * (1.0f / HH);
        float var = S2 * (1.0f / HH) - mu * mu;
        out1[(size_t)(k0 + r) * HH + h] = g * (vout[r] - mu) * rsqrtf(var + LN_EPS) + bb;
    }
}

// ---- ffn hidden: h1 = relu(out1 @ W1.T + b1) ----
__global__ __launch_bounds__(512) void ffn1_kernel(const float* __restrict__ out1,
                                                   const float* __restrict__ W1T,
                                                   const float* __restrict__ b1,
                                                   float* __restrict__ h1) {
    int k0 = blockIdx.x * 4;
    int h = threadIdx.x;
    __shared__ float os[4][512];
    #pragma unroll
    for (int r = 0; r < 4; r++) os[r][h] = out1[(size_t)(k0 + r) * HH + h];
    __syncthreads();
    float acc[4] = {0.f, 0.f, 0.f, 0.f};
    for (int j = 0; j < HH; j++) {
        float wv = W1T[(size_t)j * HH + h];
        #pragma unroll
        for (int r = 0; r < 4; r++) acc[r] += os[r][j] * wv;
    }
    float b = b1[h];
    #pragma unroll
    for (int r = 0; r < 4; r++)
        h1[(size_t)(k0 + r) * HH + h] = fmaxf(acc[r] + b, 0.f);
}

// ---- ffn out + residual + LayerNorm 2 -> out ----
__global__ __launch_bounds__(512) void ffn2_ln2_kernel(
    const float* __restrict__ h1, const float* __restrict__ W2T,
    const float* __restrict__ b2, const float* __restrict__ out1,
    const float* __restrict__ ln_g, const float* __restrict__ ln_b,
    float* __restrict__ out) {
    int k0 = blockIdx.x * 4;
    int h = threadIdx.x;
    int w = h >> 6, lane = h & 63;
    __shared__ float hs[4][512];
    #pragma unroll
    for (int r = 0; r < 4; r++) hs[r][h] = h1[(size_t)(k0 + r) * HH + h];
    __syncthreads();
    float acc[4] = {0.f, 0.f, 0.f, 0.f};
    for (int j = 0; j < HH; j++) {
        float wv = W2T[(size_t)j * HH + h];
        #pragma unroll
        for (int r = 0; r < 4; r++) acc[r] += hs[r][j] * wv;
    }
    float b = b2[h];
    float g = ln_g[h], bb = ln_b[h];
    __shared__ float red1[8][4], red2[8][4];
    float vout[4];
    #pragma unroll
    for (int r = 0; r < 4; r++) {
        float v = out1[(size_t)(k0 + r) * HH + h] + acc[r] + b;
        vout[r] = v;
        float s1 = wave_reduce_sum(v);
        float s2 = wave_reduce_sum(v * v);
        if (lane == 0) { red1[w][r] = s1; red2[w][r] = s2; }
    }
    __syncthreads();
    #pragma unroll
    for (int r = 0; r < 4; r++) {
        float S1 = 0.f, S2 = 0.f;
        #pragma unroll
        for (int i = 0; i < 8; i++) { S1 += red1[i][r]; S2 += red2[i][r]; }
        float mu  = S1 * (1.0f / HH);
        float var = S2 * (1.0f / HH) - mu * mu;
        out[(size_t)(k0 + r) * HH + h] = g * (vout[r] - mu) * rsqrtf(var + LN_EPS) + bb;
    }
}

extern "C" void kernel_launch(void* const* d_in, const int* in_sizes, int n_in,
                              void* d_out, int out_size, void* d_ws, size_t ws_size,
                              hipStream_t stream) {
    const float* x          = (const float*)d_in[0];
    const float* pair_feats = (const float*)d_in[1];
    const float* W_att      = (const float*)d_in[2];
    const float* b_att      = (const float*)d_in[3];
    const float* W_obj      = (const float*)d_in[4];
    const float* b_obj      = (const float*)d_in[5];
    const float* W_pair     = (const float*)d_in[6];
    const float* b_pair     = (const float*)d_in[7];
    const float* ln_g       = (const float*)d_in[8];
    const float* ln_b       = (const float*)d_in[9];
    const float* W1         = (const float*)d_in[10];
    const float* b1         = (const float*)d_in[11];
    const float* W2         = (const float*)d_in[12];
    const float* b2         = (const float*)d_in[13];
    float* out = (float*)d_out;

    float* ws        = (float*)d_ws;
    float* W_objT    = ws;                        // 512*512
    float* W1T       = W_objT + 512 * 512;        // 512*512
    float* W2T       = W1T + 512 * 512;           // 512*512
    float* W_pairT   = W2T + 512 * 512;           // 128*512
    float* sa        = W_pairT + 128 * 512;       // 512
    float* sb        = sa + 512;                  // 512
    float* A         = sb + 512;                  // 512*512
    float* apf_part  = A + 512 * 512;             // 4*512*128
    float* asum_part = apf_part + NCHUNK * 512 * 128; // 4*512
    float* oj        = asum_part + NCHUNK * 512;  // 512*512
    float* out1      = oj + 512 * 512;            // 512*512
    float* h1        = out1 + 512 * 512;          // 512*512

    dim3 tb(32, 8);
    transpose_kernel<<<dim3(16, 16), tb, 0, stream>>>(W_obj, W_objT, 512, 512);
    transpose_kernel<<<dim3(4, 16), tb, 0, stream>>>(W_pair, W_pairT, 512, 128);
    transpose_kernel<<<dim3(16, 16), tb, 0, stream>>>(W1, W1T, 512, 512);
    transpose_kernel<<<dim3(16, 16), tb, 0, stream>>>(W2, W2T, 512, 512);

    sab_kernel<<<512, 64, 0, stream>>>(x, W_att, sa, sb);
    pair_pass_kernel<<<dim3(512, NCHUNK), 512, 0, stream>>>(pair_feats, sa, sb, W_att, b_att,
                                                            A, apf_part, asum_part);
    oj_kernel<<<128, 512, 0, stream>>>(x, W_objT, b_obj, oj);
    msg_ln1_kernel<<<128, 512, 0, stream>>>(x, A, oj, apf_part, asum_part, W_pairT,
                                            b_pair, ln_g, ln_b, out1);
    ffn1_kernel<<<128, 512, 0, stream>>>(out1, W1T, b1, h1);
    ffn2_ln2_kernel<<<128, 512, 0, stream>>>(h1, W2T, b2, out1, ln_g, ln_b, out);
}

// Round 3
// 90.864 us; speedup vs baseline: 1.9433x; 1.6990x over previous
//
#include <hip/hip_runtime.h>
#include <math.h>

#define KK 512
#define DD 512
#define HH 512
#define PD 128
#define KM1 511
#define LN_EPS 1e-5f
#define NCHUNK 4
#define CHUNK_T 128

__device__ __forceinline__ float wave_reduce_sum(float v) {
    #pragma unroll
    for (int off = 32; off > 0; off >>= 1)
        v += __shfl_xor(v, off, 64);
    return v;
}

// reduce within 32-lane half-groups
__device__ __forceinline__ float half_reduce_sum(float v) {
    #pragma unroll
    for (int off = 16; off > 0; off >>= 1)
        v += __shfl_xor(v, off, 64);
    return v;
}

// ---- sa[k] = x[k,:]·wa, sb[k] = x[k,:]·wb ----
__global__ __launch_bounds__(64) void sab_kernel(const float* __restrict__ x,
                                                 const float* __restrict__ W_att,
                                                 float* __restrict__ sa,
                                                 float* __restrict__ sb) {
    int k = blockIdx.x;
    int lane = threadIdx.x;
    const float4* xr = (const float4*)(x + (size_t)k * DD);
    const float4* wa = (const float4*)(W_att);
    const float4* wb = (const float4*)(W_att + DD);
    float pa = 0.f, pb = 0.f;
    #pragma unroll
    for (int i = 0; i < 2; i++) {
        float4 xv = xr[lane + i * 64];
        float4 av = wa[lane + i * 64];
        float4 bv = wb[lane + i * 64];
        pa += xv.x * av.x + xv.y * av.y + xv.z * av.z + xv.w * av.w;
        pb += xv.x * bv.x + xv.y * bv.y + xv.z * bv.z + xv.w * bv.w;
    }
    pa = wave_reduce_sum(pa);
    pb = wave_reduce_sum(pb);
    if (lane == 0) { sa[k] = pa; sb[k] = pb; }
}

// ---- streaming pass over pair_feats, preloaded (8 loads in flight) ----
__global__ __launch_bounds__(512) void pair_pass_kernel(
    const float* __restrict__ pf, const float* __restrict__ sa,
    const float* __restrict__ sb, const float* __restrict__ W_att,
    const float* __restrict__ b_att, float* __restrict__ A,
    float* __restrict__ apf_part, float* __restrict__ asum_part) {
    int k = blockIdx.x;
    int chunk = blockIdx.y;
    int tbase = chunk * CHUNK_T;
    int tid = threadIdx.x;
    int w = tid >> 6, lane = tid & 63;
    int h = lane >> 5, c = lane & 31;
    int g = w * 2 + h;           // group 0..15, one t-row per group

    float4 wc4 = ((const float4*)(W_att + 2 * DD))[c];
    float sak = sa[k];
    float batt = b_att[0];
    const float4* pfk = (const float4*)(pf + (size_t)k * KM1 * PD);

    float4 v[8];
    int tr[8];
    #pragma unroll
    for (int it = 0; it < 8; it++) {
        int t = tbase + it * 16 + g;
        tr[it] = t;
        int tc = t < KM1 ? t : KM1 - 1;
        v[it] = pfk[(size_t)tc * 32 + c];
    }

    float a0 = 0.f, a1 = 0.f, a2 = 0.f, a3 = 0.f, asl = 0.f;
    #pragma unroll
    for (int it = 0; it < 8; it++) {
        float part = v[it].x * wc4.x + v[it].y * wc4.y + v[it].z * wc4.z + v[it].w * wc4.w;
        part = half_reduce_sum(part);
        int t = tr[it];
        int j = t + (t >= k);
        int jj = j < KK ? j : KK - 1;
        float z = sak + sb[jj] + part + batt;
        float alpha = (t < KM1) ? 1.f / (1.f + __expf(-z)) : 0.f;
        if (c == 0 && t < KM1) A[(size_t)k * KK + j] = alpha;
        a0 += alpha * v[it].x;
        a1 += alpha * v[it].y;
        a2 += alpha * v[it].z;
        a3 += alpha * v[it].w;
        asl += alpha;
    }

    __shared__ float apf_s[16][128];
    __shared__ float asum_s[16];
    apf_s[g][4 * c + 0] = a0;
    apf_s[g][4 * c + 1] = a1;
    apf_s[g][4 * c + 2] = a2;
    apf_s[g][4 * c + 3] = a3;
    if (c == 0) asum_s[g] = asl;
    __syncthreads();
    if (tid < PD) {
        float s = 0.f;
        #pragma unroll
        for (int i = 0; i < 16; i++) s += apf_s[i][tid];
        apf_part[((size_t)chunk * KK + k) * PD + tid] = s;
    }
    if (tid == 0) {
        float s = 0.f;
        #pragma unroll
        for (int i = 0; i < 16; i++) s += asum_s[i];
        asum_part[(size_t)chunk * KK + k] = s;
        if (chunk == 0) A[(size_t)k * KK + k] = 0.f;
    }
}

// ================= tiled fp32 GEMMs, 64x64 tile, 4x4/thread =================
// C_partial[z] = A[M,K-slice] · op(B);  grid (N/64, M/64, nz), block 256.

// A [M,K] row-major, B [N,K] row-major (A·B^T)
__global__ __launch_bounds__(256) void gemm64_abt(
    const float* __restrict__ Ain, const float* __restrict__ Bin,
    float* __restrict__ P, int K, int kPerZ) {
    int m0 = blockIdx.y * 64, n0 = blockIdx.x * 64;
    int z = blockIdx.z;
    int kbeg = z * kPerZ, kend = kbeg + kPerZ;
    __shared__ float As[64][68];
    __shared__ float Bs[64][68];
    int tid = threadIdx.x;
    int tx = tid & 15, ty = tid >> 4;
    float acc[4][4] = {{0.f}};
    for (int k0 = kbeg; k0 < kend; k0 += 64) {
        #pragma unroll
        for (int i = 0; i < 4; i++) {
            int f = tid + i * 256;
            int r = f >> 4;
            int c4 = f & 15;
            float4 av = *(const float4*)&Ain[(size_t)(m0 + r) * K + k0 + c4 * 4];
            As[c4 * 4 + 0][r] = av.x; As[c4 * 4 + 1][r] = av.y;
            As[c4 * 4 + 2][r] = av.z; As[c4 * 4 + 3][r] = av.w;
            float4 bv = *(const float4*)&Bin[(size_t)(n0 + r) * K + k0 + c4 * 4];
            Bs[c4 * 4 + 0][r] = bv.x; Bs[c4 * 4 + 1][r] = bv.y;
            Bs[c4 * 4 + 2][r] = bv.z; Bs[c4 * 4 + 3][r] = bv.w;
        }
        __syncthreads();
        #pragma unroll
        for (int kk = 0; kk < 64; kk++) {
            float4 a = *(const float4*)&As[kk][ty * 4];
            float4 b = *(const float4*)&Bs[kk][tx * 4];
            acc[0][0] += a.x * b.x; acc[0][1] += a.x * b.y; acc[0][2] += a.x * b.z; acc[0][3] += a.x * b.w;
            acc[1][0] += a.y * b.x; acc[1][1] += a.y * b.y; acc[1][2] += a.y * b.z; acc[1][3] += a.y * b.w;
            acc[2][0] += a.z * b.x; acc[2][1] += a.z * b.y; acc[2][2] += a.z * b.z; acc[2][3] += a.z * b.w;
            acc[3][0] += a.w * b.x; acc[3][1] += a.w * b.y; acc[3][2] += a.w * b.z; acc[3][3] += a.w * b.w;
        }
        __syncthreads();
    }
    float* Pz = P + (size_t)z * KK * HH;
    #pragma unroll
    for (int q = 0; q < 4; q++) {
        float4 o = make_float4(acc[q][0], acc[q][1], acc[q][2], acc[q][3]);
        *(float4*)&Pz[(size_t)(m0 + ty * 4 + q) * HH + n0 + tx * 4] = o;
    }
}

// A [M,K] row-major, B [K,N=512] row-major (A·B)
__global__ __launch_bounds__(256) void gemm64_ab(
    const float* __restrict__ Ain, const float* __restrict__ Bin,
    float* __restrict__ P, int K, int kPerZ) {
    int m0 = blockIdx.y * 64, n0 = blockIdx.x * 64;
    int z = blockIdx.z;
    int kbeg = z * kPerZ, kend = kbeg + kPerZ;
    __shared__ float As[64][68];
    __shared__ float Bs[64][68];
    int tid = threadIdx.x;
    int tx = tid & 15, ty = tid >> 4;
    float acc[4][4] = {{0.f}};
    for (int k0 = kbeg; k0 < kend; k0 += 64) {
        #pragma unroll
        for (int i = 0; i < 4; i++) {
            int f = tid + i * 256;
            int r = f >> 4;
            int c4 = f & 15;
            float4 av = *(const float4*)&Ain[(size_t)(m0 + r) * K + k0 + c4 * 4];
            As[c4 * 4 + 0][r] = av.x; As[c4 * 4 + 1][r] = av.y;
            As[c4 * 4 + 2][r] = av.z; As[c4 * 4 + 3][r] = av.w;
            // B: rows k0+r2 (64), cols n0..n0+63
            int r2 = f >> 4;     // reuse: 64 rows, 16 float4 per row
            float4 bv = *(const float4*)&Bin[(size_t)(k0 + r2) * HH + n0 + c4 * 4];
            *(float4*)&Bs[r2][c4 * 4] = bv;
        }
        __syncthreads();
        #pragma unroll
        for (int kk = 0; kk < 64; kk++) {
            float4 a = *(const float4*)&As[kk][ty * 4];
            float4 b = *(const float4*)&Bs[kk][tx * 4];
            acc[0][0] += a.x * b.x; acc[0][1] += a.x * b.y; acc[0][2] += a.x * b.z; acc[0][3] += a.x * b.w;
            acc[1][0] += a.y * b.x; acc[1][1] += a.y * b.y; acc[1][2] += a.y * b.z; acc[1][3] += a.y * b.w;
            acc[2][0] += a.z * b.x; acc[2][1] += a.z * b.y; acc[2][2] += a.z * b.z; acc[2][3] += a.z * b.w;
            acc[3][0] += a.w * b.x; acc[3][1] += a.w * b.y; acc[3][2] += a.w * b.z; acc[3][3] += a.w * b.w;
        }
        __syncthreads();
    }
    float* Pz = P + (size_t)z * KK * HH;
    #pragma unroll
    for (int q = 0; q < 4; q++) {
        float4 o = make_float4(acc[q][0], acc[q][1], acc[q][2], acc[q][3]);
        *(float4*)&Pz[(size_t)(m0 + ty * 4 + q) * HH + n0 + tx * 4] = o;
    }
}

// ---- reduce 4 slabs + bias (+relu) ----
__global__ __launch_bounds__(256) void red_bias_kernel(const float* __restrict__ P,
                                                       const float* __restrict__ bias,
                                                       float* __restrict__ C, int relu) {
    int nn = blockIdx.x * 256 + threadIdx.x;   // float4 index, 65536 total
    float4 s = ((const float4*)P)[nn];
    #pragma unroll
    for (int z = 1; z < 4; z++) {
        float4 p = ((const float4*)P)[(size_t)z * 65536 + nn];
        s.x += p.x; s.y += p.y; s.z += p.z; s.w += p.w;
    }
    float4 b4 = ((const float4*)bias)[nn & 127];
    s.x += b4.x; s.y += b4.y; s.z += b4.z; s.w += b4.w;
    if (relu) {
        s.x = fmaxf(s.x, 0.f); s.y = fmaxf(s.y, 0.f);
        s.z = fmaxf(s.z, 0.f); s.w = fmaxf(s.w, 0.f);
    }
    ((float4*)C)[nn] = s;
}

// ---- sum apf chunks ----
__global__ __launch_bounds__(256) void red_apf_kernel(const float* __restrict__ apf_part,
                                                      float* __restrict__ apf) {
    int nn = blockIdx.x * 256 + threadIdx.x;   // float4 index, 16384 total
    float4 s = ((const float4*)apf_part)[nn];
    #pragma unroll
    for (int z = 1; z < NCHUNK; z++) {
        float4 p = ((const float4*)apf_part)[(size_t)z * 16384 + nn];
        s.x += p.x; s.y += p.y; s.z += p.z; s.w += p.w;
    }
    ((float4*)apf)[nn] = s;
}

// ---- reduce 5 msg slabs + asum*b_pair + x residual + LayerNorm1 -> out1 ----
__global__ __launch_bounds__(128) void red_msg_ln1(
    const float* __restrict__ P, const float* __restrict__ x,
    const float* __restrict__ asum_part, const float* __restrict__ b_pair,
    const float* __restrict__ ln_g, const float* __restrict__ ln_b,
    float* __restrict__ out1) {
    int k = blockIdx.x;
    int t = threadIdx.x;            // float4 col 0..127
    int w = t >> 6, lane = t & 63;
    float4 s = ((const float4*)(P + (size_t)k * HH))[t];
    #pragma unroll
    for (int z = 1; z < 5; z++) {
        float4 p = ((const float4*)(P + (size_t)z * KK * HH + (size_t)k * HH))[t];
        s.x += p.x; s.y += p.y; s.z += p.z; s.w += p.w;
    }
    float as = asum_part[k] + asum_part[KK + k] + asum_part[2 * KK + k] + asum_part[3 * KK + k];
    float4 bp = ((const float4*)b_pair)[t];
    float4 xr = ((const float4*)(x + (size_t)k * DD))[t];
    const float inv = 1.0f / (float)KM1;
    float4 vv;
    vv.x = xr.x + (s.x + as * bp.x) * inv;
    vv.y = xr.y + (s.y + as * bp.y) * inv;
    vv.z = xr.z + (s.z + as * bp.z) * inv;
    vv.w = xr.w + (s.w + as * bp.w) * inv;
    float s1 = vv.x + vv.y + vv.z + vv.w;
    float s2 = vv.x * vv.x + vv.y * vv.y + vv.z * vv.z + vv.w * vv.w;
    s1 = wave_reduce_sum(s1);
    s2 = wave_reduce_sum(s2);
    __shared__ float r1[2], r2[2];
    if (lane == 0) { r1[w] = s1; r2[w] = s2; }
    __syncthreads();
    float S1 = r1[0] + r1[1], S2 = r2[0] + r2[1];
    float mu = S1 * (1.0f / HH);
    float var = S2 * (1.0f / HH) - mu * mu;
    float rs = rsqrtf(var + LN_EPS);
    float4 g4 = ((const float4*)ln_g)[t];
    float4 b4 = ((const float4*)ln_b)[t];
    float4 o;
    o.x = g4.x * (vv.x - mu) * rs + b4.x;
    o.y = g4.y * (vv.y - mu) * rs + b4.y;
    o.z = g4.z * (vv.z - mu) * rs + b4.z;
    o.w = g4.w * (vv.w - mu) * rs + b4.w;
    ((float4*)(out1 + (size_t)k * HH))[t] = o;
}

// ---- reduce 4 ffn2 slabs + b2 + out1 residual + LayerNorm2 -> out ----
__global__ __launch_bounds__(128) void red_ffn2_ln2(
    const float* __restrict__ P, const float* __restrict__ out1,
    const float* __restrict__ b2, const float* __restrict__ ln_g,
    const float* __restrict__ ln_b, float* __restrict__ out) {
    int k = blockIdx.x;
    int t = threadIdx.x;
    int w = t >> 6, lane = t & 63;
    float4 s = ((const float4*)(P + (size_t)k * HH))[t];
    #pragma unroll
    for (int z = 1; z < 4; z++) {
        float4 p = ((const float4*)(P + (size_t)z * KK * HH + (size_t)k * HH))[t];
        s.x += p.x; s.y += p.y; s.z += p.z; s.w += p.w;
    }
    float4 b4v = ((const float4*)b2)[t];
    float4 xr = ((const float4*)(out1 + (size_t)k * HH))[t];
    float4 vv;
    vv.x = xr.x + s.x + b4v.x;
    vv.y = xr.y + s.y + b4v.y;
    vv.z = xr.z + s.z + b4v.z;
    vv.w = xr.w + s.w + b4v.w;
    float s1 = vv.x + vv.y + vv.z + vv.w;
    float s2 = vv.x * vv.x + vv.y * vv.y + vv.z * vv.z + vv.w * vv.w;
    s1 = wave_reduce_sum(s1);
    s2 = wave_reduce_sum(s2);
    __shared__ float r1[2], r2[2];
    if (lane == 0) { r1[w] = s1; r2[w] = s2; }
    __syncthreads();
    float S1 = r1[0] + r1[1], S2 = r2[0] + r2[1];
    float mu = S1 * (1.0f / HH);
    float var = S2 * (1.0f / HH) - mu * mu;
    float rs = rsqrtf(var + LN_EPS);
    float4 g4 = ((const float4*)ln_g)[t];
    float4 b4 = ((const float4*)ln_b)[t];
    float4 o;
    o.x = g4.x * (vv.x - mu) * rs + b4.x;
    o.y = g4.y * (vv.y - mu) * rs + b4.y;
    o.z = g4.z * (vv.z - mu) * rs + b4.z;
    o.w = g4.w * (vv.w - mu) * rs + b4.w;
    ((float4*)(out + (size_t)k * HH))[t] = o;
}

extern "C" void kernel_launch(void* const* d_in, const int* in_sizes, int n_in,
                              void* d_out, int out_size, void* d_ws, size_t ws_size,
                              hipStream_t stream) {
    const float* x          = (const float*)d_in[0];
    const float* pair_feats = (const float*)d_in[1];
    const float* W_att      = (const float*)d_in[2];
    const float* b_att      = (const float*)d_in[3];
    const float* W_obj      = (const float*)d_in[4];
    const float* b_obj      = (const float*)d_in[5];
    const float* W_pair     = (const float*)d_in[6];
    const float* b_pair     = (const float*)d_in[7];
    const float* ln_g       = (const float*)d_in[8];
    const float* ln_b       = (const float*)d_in[9];
    const float* W1         = (const float*)d_in[10];
    const float* b1         = (const float*)d_in[11];
    const float* W2         = (const float*)d_in[12];
    const float* b2         = (const float*)d_in[13];
    float* out = (float*)d_out;

    const size_t MAT = (size_t)KK * HH;       // 262144
    float* ws        = (float*)d_ws;
    float* sa        = ws;                    // 512
    float* sb        = sa + KK;               // 512
    float* A         = sb + KK;               // MAT
    float* apf_part  = A + MAT;               // 4*512*128
    float* asum_part = apf_part + NCHUNK * KK * PD;  // 4*512
    float* apf       = asum_part + NCHUNK * KK;      // 512*128
    float* oj        = apf + KK * PD;         // MAT
    float* out1      = oj + MAT;              // MAT
    float* h1        = out1 + MAT;            // MAT
    float* P_oj      = h1 + MAT;              // 4*MAT
    float* P_msg     = P_oj + 4 * MAT;        // 5*MAT
    float* P_f1      = P_msg + 5 * MAT;       // 4*MAT
    float* P_f2      = P_f1 + 4 * MAT;        // 4*MAT

    sab_kernel<<<512, 64, 0, stream>>>(x, W_att, sa, sb);
    pair_pass_kernel<<<dim3(512, NCHUNK), 512, 0, stream>>>(pair_feats, sa, sb, W_att, b_att,
                                                            A, apf_part, asum_part);
    red_apf_kernel<<<64, 256, 0, stream>>>(apf_part, apf);

    // oj = x · W_obj^T + b_obj
    gemm64_abt<<<dim3(8, 8, 4), 256, 0, stream>>>(x, W_obj, P_oj, DD, 128);
    red_bias_kernel<<<256, 256, 0, stream>>>(P_oj, b_obj, oj, 0);

    // msg = A · oj  (slabs 0..3)  +  apf · W_pair^T  (slab 4)
    gemm64_ab<<<dim3(8, 8, 4), 256, 0, stream>>>(A, oj, P_msg, KK, 128);
    gemm64_abt<<<dim3(8, 8, 1), 256, 0, stream>>>(apf, W_pair, P_msg + 4 * MAT, PD, 128);
    red_msg_ln1<<<512, 128, 0, stream>>>(P_msg, x, asum_part, b_pair, ln_g, ln_b, out1);

    // ffn1: h1 = relu(out1 · W1^T + b1)
    gemm64_abt<<<dim3(8, 8, 4), 256, 0, stream>>>(out1, W1, P_f1, HH, 128);
    red_bias_kernel<<<256, 256, 0, stream>>>(P_f1, b1, h1, 1);

    // ffn2 + LN2
    gemm64_abt<<<dim3(8, 8, 4), 256, 0, stream>>>(h1, W2, P_f2, HH, 128);
    red_ffn2_ln2<<<512, 128, 0, stream>>>(P_f2, out1, b2, ln_g, ln_b, out);
}